// Round 2
// baseline (1346.793 us; speedup 1.0000x reference)
//
#include <hip/hip_runtime.h>
#include <stdint.h>

#define HH 1024
#define WW 2048
#define HWN (HH*WW)          // 2097152
#define BIGL HWN             // 'no cluster' sentinel
#define NSLOTS 26
#define MINCL 30
#define THREADS 256
#define MAXCAND 70000        // >= HWN/30 + 1

// ---------------- union-find (lock-free, min-root) ----------------
__device__ __forceinline__ int uf_load(int* p, int i) {
    return __hip_atomic_load(&p[i], __ATOMIC_RELAXED, __HIP_MEMORY_SCOPE_AGENT);
}
__device__ __forceinline__ void uf_store(int* p, int i, int v) {
    __hip_atomic_store(&p[i], v, __ATOMIC_RELAXED, __HIP_MEMORY_SCOPE_AGENT);
}
__device__ int uf_find(int* parent, int x) {
    int p = uf_load(parent, x);
    while (p != x) {
        int gp = uf_load(parent, p);
        if (gp != p) uf_store(parent, x, gp);   // path halving (benign race)
        x = p; p = gp;
    }
    return x;
}
__device__ void uf_union(int* parent, int a, int b) {
    int ra = uf_find(parent, a);
    int rb = uf_find(parent, b);
    while (ra != rb) {
        if (ra > rb) { int t = ra; ra = rb; rb = t; }   // ra < rb: hook rb under ra
        int old = atomicCAS(&parent[rb], rb, ra);
        if (old == rb) return;
        rb = uf_find(parent, old);
        ra = uf_find(parent, ra);
    }
}

// ---------------- stage kernels ----------------
// flags bit0 = active, bit1 = core; parent[i] = i
__global__ __launch_bounds__(THREADS) void k_init(const float* __restrict__ mask,
                                                  uint8_t* __restrict__ flags,
                                                  int* __restrict__ parent) {
    int i = blockIdx.x * THREADS + threadIdx.x;
    int r = i >> 11, c = i & (WW - 1);
    bool act = mask[i] > 0.1f;
    int cnt = 0;
    #pragma unroll
    for (int dr = -1; dr <= 1; ++dr) {
        int rr = r + dr;
        if (rr < 0 || rr >= HH) continue;
        #pragma unroll
        for (int dc = -1; dc <= 1; ++dc) {
            int cc = c + dc;
            if (cc < 0 || cc >= WW) continue;
            cnt += (mask[rr * WW + cc] > 0.1f) ? 1 : 0;
        }
    }
    bool core = act && (cnt >= 4);   // cnt includes self; MIN_SAMPLES = 4
    flags[i] = (uint8_t)((act ? 1 : 0) | (core ? 2 : 0));
    parent[i] = i;
}

// process 4 backward edges per core pixel (covers each 8-neighbor edge once)
__global__ __launch_bounds__(THREADS) void k_union(const uint8_t* __restrict__ flags,
                                                   int* __restrict__ parent) {
    int i = blockIdx.x * THREADS + threadIdx.x;
    if (!(flags[i] & 2)) return;
    int r = i >> 11, c = i & (WW - 1);
    if (c > 0 && (flags[i - 1] & 2)) uf_union(parent, i, i - 1);
    if (r > 0) {
        if (c > 0        && (flags[i - WW - 1] & 2)) uf_union(parent, i, i - WW - 1);
        if (                (flags[i - WW    ] & 2)) uf_union(parent, i, i - WW);
        if (c < WW - 1   && (flags[i - WW + 1] & 2)) uf_union(parent, i, i - WW + 1);
    }
}

__global__ __launch_bounds__(THREADS) void k_flatten(const uint8_t* __restrict__ flags,
                                                     int* __restrict__ parent,
                                                     int* __restrict__ finalL) {
    int i = blockIdx.x * THREADS + threadIdx.x;
    finalL[i] = (flags[i] & 2) ? uf_find(parent, i) : BIGL;
}

// border assignment + per-label stats (wave-run-aggregated atomics)
__global__ __launch_bounds__(THREADS) void k_border_stats(
        const uint8_t* __restrict__ flags, const int* __restrict__ finalL,
        int* __restrict__ labfull, int* __restrict__ sizes,
        unsigned long long* __restrict__ colsum) {
    int i = blockIdx.x * THREADS + threadIdx.x;
    int f = flags[i];
    int lab = BIGL;
    if (f & 2) {
        lab = finalL[i];
    } else if (f & 1) {              // active non-core: min core label in 3x3
        int r = i >> 11, c = i & (WW - 1);
        int m = BIGL;
        #pragma unroll
        for (int dr = -1; dr <= 1; ++dr) {
            int rr = r + dr;
            if (rr < 0 || rr >= HH) continue;
            #pragma unroll
            for (int dc = -1; dc <= 1; ++dc) {
                int cc = c + dc;
                if (cc < 0 || cc >= WW) continue;
                int v = finalL[rr * WW + cc];
                if (v < m) m = v;
            }
        }
        lab = m;                     // BIGL if no core neighbor
    }
    labfull[i] = lab;

    // wave-level run aggregation: lanes = consecutive columns of one row
    // (WW % 64 == 0 so a wave never crosses a row boundary)
    int lane = threadIdx.x & 63;
    int labp = __shfl_up(lab, 1);
    bool head = (lane == 0) || (labp != lab);
    unsigned long long hm = __ballot(head);
    if (head && lab < BIGL) {
        unsigned long long rest = (hm >> lane) >> 1;   // heads above this lane
        int len = rest ? __ffsll((unsigned long long)rest) : (64 - lane);
        long long c0 = (long long)(i & (WW - 1));
        // run covers columns c0 .. c0+len-1 (same label)
        atomicAdd(&sizes[lab], len);
        atomicAdd(&colsum[lab],
                  (unsigned long long)(c0 * len + (long long)len * (len - 1) / 2));
    }
}

__global__ __launch_bounds__(THREADS) void k_cands(const int* __restrict__ sizes,
                                                   const unsigned long long* __restrict__ colsum,
                                                   unsigned long long* __restrict__ cand,
                                                   int* __restrict__ counter) {
    int i = blockIdx.x * THREADS + threadIdx.x;
    int s = sizes[i];
    if (s >= MINCL) {
        float mean = (float)colsum[i] / (float)s;
        unsigned int mb = __float_as_uint(mean);      // mean >= 0: bits order = value order
        unsigned long long key = ((unsigned long long)mb << 32) | (unsigned int)i;
        int p = atomicAdd(counter, 1);
        cand[p] = key;
    }
}

// single block: 26 successive min-extractions; writes root -> channel map
__global__ __launch_bounds__(1024) void k_select(const unsigned long long* __restrict__ cand,
                                                 const int* __restrict__ counter,
                                                 signed char* __restrict__ chan) {
    __shared__ unsigned long long sm[1024];
    const int tid = threadIdx.x;
    const int n = *counter;
    unsigned long long prev = 0;
    for (int k = 0; k < NSLOTS; ++k) {
        unsigned long long local = ~0ull;
        for (int j = tid; j < n; j += 1024) {
            unsigned long long v = cand[j];
            if ((k == 0 || v > prev) && v < local) local = v;
        }
        sm[tid] = local;
        __syncthreads();
        for (int s = 512; s > 0; s >>= 1) {
            if (tid < s && sm[tid + s] < sm[tid]) sm[tid] = sm[tid + s];
            __syncthreads();
        }
        unsigned long long best = sm[0];
        __syncthreads();                  // protect sm reuse next iteration
        if (best == ~0ull) break;         // uniform: fewer than 26 valid clusters
        if (tid == 0) chan[(unsigned int)(best & 0xFFFFFFFFull)] = (signed char)k;
        prev = best;
    }
}

// one-hot 26xHxW int32 output (harness reads int32), int4 stores
__global__ __launch_bounds__(THREADS) void k_output(const int* __restrict__ labfull,
                                                    const signed char* __restrict__ chan,
                                                    int* __restrict__ out) {
    int i4 = (blockIdx.x * THREADS + threadIdx.x) * 4;
    int chv[4];
    #pragma unroll
    for (int t = 0; t < 4; ++t) {
        int lab = labfull[i4 + t];
        chv[t] = (lab < BIGL) ? (int)chan[lab] : -1;
    }
    #pragma unroll
    for (int c = 0; c < NSLOTS; ++c) {
        int4 v;
        v.x = (chv[0] == c) ? 1 : 0;
        v.y = (chv[1] == c) ? 1 : 0;
        v.z = (chv[2] == c) ? 1 : 0;
        v.w = (chv[3] == c) ? 1 : 0;
        *(int4*)(out + (size_t)c * HWN + i4) = v;
    }
}

extern "C" void kernel_launch(void* const* d_in, const int* in_sizes, int n_in,
                              void* d_out, int out_size, void* d_ws, size_t ws_size,
                              hipStream_t stream) {
    const float* mask = (const float*)d_in[0];
    int* out = (int*)d_out;

    char* w = (char*)d_ws;
    int* parent                 = (int*)(w);                          //  8 MB (reused as labfull)
    int* finalL                 = (int*)(w + (size_t)HWN * 4);        //  8 MB
    int* sizes                  = (int*)(w + (size_t)HWN * 8);        //  8 MB
    unsigned long long* colsum  = (unsigned long long*)(w + (size_t)HWN * 12); // 16 MB
    uint8_t* flags              = (uint8_t*)(w + (size_t)HWN * 20);   //  2 MB
    signed char* chan           = (signed char*)(w + (size_t)HWN * 21); // 2 MB
    unsigned long long* cand    = (unsigned long long*)(w + (size_t)HWN * 22); // 560 KB
    int* counter                = (int*)(w + (size_t)HWN * 22 + MAXCAND * 8);

    // ws is re-poisoned 0xAA before every call — re-init what we accumulate into
    hipMemsetAsync(sizes, 0, (size_t)HWN * 4, stream);
    hipMemsetAsync(colsum, 0, (size_t)HWN * 8, stream);
    hipMemsetAsync(chan, 0xFF, (size_t)HWN, stream);    // -1 = no channel
    hipMemsetAsync(counter, 0, 4, stream);

    const int blocks = HWN / THREADS;   // 8192
    k_init        <<<blocks, THREADS, 0, stream>>>(mask, flags, parent);
    k_union       <<<blocks, THREADS, 0, stream>>>(flags, parent);
    k_flatten     <<<blocks, THREADS, 0, stream>>>(flags, parent, finalL);
    k_border_stats<<<blocks, THREADS, 0, stream>>>(flags, finalL, parent, sizes, colsum);
    k_cands       <<<blocks, THREADS, 0, stream>>>(sizes, colsum, cand, counter);
    k_select      <<<1, 1024, 0, stream>>>(cand, counter, chan);
    k_output      <<<HWN / (4 * THREADS), THREADS, 0, stream>>>(parent, chan, out);
}

// Round 3
// 657.425 us; speedup vs baseline: 2.0486x; 2.0486x over previous
//
#include <hip/hip_runtime.h>
#include <stdint.h>

#define HH 1024
#define WW 2048
#define HWN (HH*WW)          // 2097152
#define BIGL HWN             // 'no cluster' sentinel
#define NSLOTS 26
#define MINCL 30
#define THREADS 256
#define MAXCAND 70000        // >= HWN/30 + 1
#define HSZ 512              // per-block LDS label-hash entries (strip touches <=256 labels)

// ---------------- union-find (lock-free, min-root) ----------------
__device__ __forceinline__ int uf_load(int* p, int i) {
    return __hip_atomic_load(&p[i], __ATOMIC_RELAXED, __HIP_MEMORY_SCOPE_AGENT);
}
__device__ __forceinline__ void uf_store(int* p, int i, int v) {
    __hip_atomic_store(&p[i], v, __ATOMIC_RELAXED, __HIP_MEMORY_SCOPE_AGENT);
}
__device__ int uf_find(int* parent, int x) {
    int p = uf_load(parent, x);
    while (p != x) {
        int gp = uf_load(parent, p);
        if (gp != p) uf_store(parent, x, gp);   // path halving (benign race)
        x = p; p = gp;
    }
    return p;
}
__device__ void uf_union(int* parent, int a, int b) {
    int ra = uf_find(parent, a);
    int rb = uf_find(parent, b);
    while (ra != rb) {
        if (ra > rb) { int t = ra; ra = rb; rb = t; }   // ra < rb: hook rb under ra
        int old = atomicCAS(&parent[rb], rb, ra);
        if (old == rb) return;
        rb = uf_find(parent, old);
        ra = uf_find(parent, ra);
    }
}

// ---------------- stage kernels ----------------
// flags bit0 = active, bit1 = core; parent[i] = i
__global__ __launch_bounds__(THREADS) void k_init(const float* __restrict__ mask,
                                                  uint8_t* __restrict__ flags,
                                                  int* __restrict__ parent) {
    int i = blockIdx.x * THREADS + threadIdx.x;
    int r = i >> 11, c = i & (WW - 1);
    bool act = mask[i] > 0.1f;
    int cnt = 0;
    #pragma unroll
    for (int dr = -1; dr <= 1; ++dr) {
        int rr = r + dr;
        if (rr < 0 || rr >= HH) continue;
        #pragma unroll
        for (int dc = -1; dc <= 1; ++dc) {
            int cc = c + dc;
            if (cc < 0 || cc >= WW) continue;
            cnt += (mask[rr * WW + cc] > 0.1f) ? 1 : 0;
        }
    }
    bool core = act && (cnt >= 4);   // cnt includes self; MIN_SAMPLES = 4
    flags[i] = (uint8_t)((act ? 1 : 0) | (core ? 2 : 0));
    parent[i] = i;
}

// process 4 backward edges per core pixel (covers each 8-neighbor edge once)
__global__ __launch_bounds__(THREADS) void k_union(const uint8_t* __restrict__ flags,
                                                   int* __restrict__ parent) {
    int i = blockIdx.x * THREADS + threadIdx.x;
    if (!(flags[i] & 2)) return;
    int r = i >> 11, c = i & (WW - 1);
    if (c > 0 && (flags[i - 1] & 2)) uf_union(parent, i, i - 1);
    if (r > 0) {
        if (c > 0        && (flags[i - WW - 1] & 2)) uf_union(parent, i, i - WW - 1);
        if (                (flags[i - WW    ] & 2)) uf_union(parent, i, i - WW);
        if (c < WW - 1   && (flags[i - WW + 1] & 2)) uf_union(parent, i, i - WW + 1);
    }
}

__global__ __launch_bounds__(THREADS) void k_flatten(const uint8_t* __restrict__ flags,
                                                     int* __restrict__ parent,
                                                     int* __restrict__ finalL) {
    int i = blockIdx.x * THREADS + threadIdx.x;
    finalL[i] = (flags[i] & 2) ? uf_find(parent, i) : BIGL;
}

// border assignment + per-label stats.
// Atomic-contention fix: wave-run aggregation -> per-block LDS hash -> one
// global atomic pair per distinct label per block (giant percolation cluster
// otherwise serializes ~1e6 atomics on one address).
__global__ __launch_bounds__(THREADS) void k_border_stats(
        const uint8_t* __restrict__ flags, const int* __restrict__ finalL,
        int* __restrict__ labfull, int* __restrict__ sizes,
        unsigned long long* __restrict__ colsum) {
    __shared__ int h_lab[HSZ];
    __shared__ int h_sz[HSZ];
    __shared__ unsigned long long h_cs[HSZ];
    for (int t = threadIdx.x; t < HSZ; t += THREADS) {
        h_lab[t] = -1; h_sz[t] = 0; h_cs[t] = 0;
    }
    __syncthreads();

    int i = blockIdx.x * THREADS + threadIdx.x;
    int f = flags[i];
    int lab = BIGL;
    if (f & 2) {
        lab = finalL[i];
    } else if (f & 1) {              // active non-core: min core label in 3x3
        int r = i >> 11, c = i & (WW - 1);
        int m = BIGL;
        #pragma unroll
        for (int dr = -1; dr <= 1; ++dr) {
            int rr = r + dr;
            if (rr < 0 || rr >= HH) continue;
            #pragma unroll
            for (int dc = -1; dc <= 1; ++dc) {
                int cc = c + dc;
                if (cc < 0 || cc >= WW) continue;
                int v = finalL[rr * WW + cc];
                if (v < m) m = v;
            }
        }
        lab = m;                     // BIGL if no core neighbor
    }
    labfull[i] = lab;

    // wave-level run aggregation: lanes = consecutive columns of one row
    // (WW % 64 == 0 so a wave never crosses a row boundary)
    int lane = threadIdx.x & 63;
    int labp = __shfl_up(lab, 1);
    bool head = (lane == 0) || (labp != lab);
    unsigned long long hm = __ballot(head);
    if (head && lab < BIGL) {
        unsigned long long rest = (hm >> lane) >> 1;   // heads above this lane
        int len = rest ? __ffsll((unsigned long long)rest) : (64 - lane);
        long long c0 = (long long)(i & (WW - 1));
        unsigned long long csum =
            (unsigned long long)(c0 * len + (long long)len * (len - 1) / 2);
        // LDS hash insert (open addressing; table can't overflow: <=256 labels/strip)
        unsigned slot = (((unsigned)lab * 2654435761u) >> 20) & (HSZ - 1);
        for (;;) {
            int old = atomicCAS(&h_lab[slot], -1, lab);
            if (old == -1 || old == lab) {
                atomicAdd(&h_sz[slot], len);
                atomicAdd(&h_cs[slot], csum);
                break;
            }
            slot = (slot + 1) & (HSZ - 1);
        }
    }
    __syncthreads();
    for (int t = threadIdx.x; t < HSZ; t += THREADS) {
        int lb = h_lab[t];
        if (lb >= 0) {
            atomicAdd(&sizes[lb], h_sz[t]);
            atomicAdd(&colsum[lb], h_cs[t]);
        }
    }
}

__global__ __launch_bounds__(THREADS) void k_cands(const int* __restrict__ sizes,
                                                   const unsigned long long* __restrict__ colsum,
                                                   unsigned long long* __restrict__ cand,
                                                   int* __restrict__ counter) {
    int i = blockIdx.x * THREADS + threadIdx.x;
    int s = sizes[i];
    if (s >= MINCL) {
        float mean = (float)colsum[i] / (float)s;
        unsigned int mb = __float_as_uint(mean);      // mean >= 0: bits order = value order
        unsigned long long key = ((unsigned long long)mb << 32) | (unsigned int)i;
        int p = atomicAdd(counter, 1);
        cand[p] = key;
    }
}

// single block: 26 successive min-extractions; writes root -> channel map
__global__ __launch_bounds__(1024) void k_select(const unsigned long long* __restrict__ cand,
                                                 const int* __restrict__ counter,
                                                 signed char* __restrict__ chan) {
    __shared__ unsigned long long sm[1024];
    const int tid = threadIdx.x;
    const int n = *counter;
    unsigned long long prev = 0;
    for (int k = 0; k < NSLOTS; ++k) {
        unsigned long long local = ~0ull;
        for (int j = tid; j < n; j += 1024) {
            unsigned long long v = cand[j];
            if ((k == 0 || v > prev) && v < local) local = v;
        }
        sm[tid] = local;
        __syncthreads();
        for (int s = 512; s > 0; s >>= 1) {
            if (tid < s && sm[tid + s] < sm[tid]) sm[tid] = sm[tid + s];
            __syncthreads();
        }
        unsigned long long best = sm[0];
        __syncthreads();                  // protect sm reuse next iteration
        if (best == ~0ull) break;         // uniform: fewer than 26 valid clusters
        if (tid == 0) chan[(unsigned int)(best & 0xFFFFFFFFull)] = (signed char)k;
        prev = best;
    }
}

// one-hot 26xHxW int32 output (harness reads int32), int4 stores
__global__ __launch_bounds__(THREADS) void k_output(const int* __restrict__ labfull,
                                                    const signed char* __restrict__ chan,
                                                    int* __restrict__ out) {
    int i4 = (blockIdx.x * THREADS + threadIdx.x) * 4;
    int chv[4];
    #pragma unroll
    for (int t = 0; t < 4; ++t) {
        int lab = labfull[i4 + t];
        chv[t] = (lab < BIGL) ? (int)chan[lab] : -1;
    }
    #pragma unroll
    for (int c = 0; c < NSLOTS; ++c) {
        int4 v;
        v.x = (chv[0] == c) ? 1 : 0;
        v.y = (chv[1] == c) ? 1 : 0;
        v.z = (chv[2] == c) ? 1 : 0;
        v.w = (chv[3] == c) ? 1 : 0;
        *(int4*)(out + (size_t)c * HWN + i4) = v;
    }
}

extern "C" void kernel_launch(void* const* d_in, const int* in_sizes, int n_in,
                              void* d_out, int out_size, void* d_ws, size_t ws_size,
                              hipStream_t stream) {
    const float* mask = (const float*)d_in[0];
    int* out = (int*)d_out;

    char* w = (char*)d_ws;
    int* parent                 = (int*)(w);                          //  8 MB (reused as labfull)
    int* finalL                 = (int*)(w + (size_t)HWN * 4);        //  8 MB
    int* sizes                  = (int*)(w + (size_t)HWN * 8);        //  8 MB
    unsigned long long* colsum  = (unsigned long long*)(w + (size_t)HWN * 12); // 16 MB
    uint8_t* flags              = (uint8_t*)(w + (size_t)HWN * 20);   //  2 MB
    signed char* chan           = (signed char*)(w + (size_t)HWN * 21); // 2 MB
    unsigned long long* cand    = (unsigned long long*)(w + (size_t)HWN * 22); // 560 KB
    int* counter                = (int*)(w + (size_t)HWN * 22 + MAXCAND * 8);

    // ws is re-poisoned 0xAA before every call — re-init what we accumulate into
    hipMemsetAsync(sizes, 0, (size_t)HWN * 4, stream);
    hipMemsetAsync(colsum, 0, (size_t)HWN * 8, stream);
    hipMemsetAsync(chan, 0xFF, (size_t)HWN, stream);    // -1 = no channel
    hipMemsetAsync(counter, 0, 4, stream);

    const int blocks = HWN / THREADS;   // 8192
    k_init        <<<blocks, THREADS, 0, stream>>>(mask, flags, parent);
    k_union       <<<blocks, THREADS, 0, stream>>>(flags, parent);
    k_flatten     <<<blocks, THREADS, 0, stream>>>(flags, parent, finalL);
    k_border_stats<<<blocks, THREADS, 0, stream>>>(flags, finalL, parent, sizes, colsum);
    k_cands       <<<blocks, THREADS, 0, stream>>>(sizes, colsum, cand, counter);
    k_select      <<<1, 1024, 0, stream>>>(cand, counter, chan);
    k_output      <<<HWN / (4 * THREADS), THREADS, 0, stream>>>(parent, chan, out);
}

// Round 4
// 436.487 us; speedup vs baseline: 3.0855x; 1.5062x over previous
//
#include <hip/hip_runtime.h>
#include <stdint.h>

#define HH 1024
#define WW 2048
#define HWN (HH*WW)          // 2097152
#define BIGL HWN             // 'no cluster' sentinel
#define NSLOTS 26
#define MINCL 30
#define THREADS 256
#define MAXCAND 70000        // >= HWN/30 + 1
#define HSZ 512              // per-block LDS label-hash entries
#define TILE 4096            // 64x64 tile
#define NTILES 512           // (1024/64)*(2048/64)

// ---------------- global union-find (lock-free, min-root) ----------------
__device__ __forceinline__ int uf_load(int* p, int i) {
    return __hip_atomic_load(&p[i], __ATOMIC_RELAXED, __HIP_MEMORY_SCOPE_AGENT);
}
__device__ __forceinline__ void uf_store(int* p, int i, int v) {
    __hip_atomic_store(&p[i], v, __ATOMIC_RELAXED, __HIP_MEMORY_SCOPE_AGENT);
}
__device__ int uf_find(int* parent, int x) {
    int p = uf_load(parent, x);
    while (p != x) {
        int gp = uf_load(parent, p);
        if (gp != p) uf_store(parent, x, gp);   // path halving (benign race)
        x = p; p = gp;
    }
    return p;
}
__device__ void uf_union(int* parent, int a, int b) {
    int ra = uf_find(parent, a);
    int rb = uf_find(parent, b);
    while (ra != rb) {
        if (ra > rb) { int t = ra; ra = rb; rb = t; }   // hook larger under smaller
        int old = atomicCAS(&parent[rb], rb, ra);
        if (old == rb) return;
        rb = uf_find(parent, old);
        ra = uf_find(parent, ra);
    }
}

// ---------------- LDS union-find (block-local, min-root) ----------------
__device__ __forceinline__ int l_load(int* p, int i) {
    return __hip_atomic_load(&p[i], __ATOMIC_RELAXED, __HIP_MEMORY_SCOPE_WORKGROUP);
}
__device__ __forceinline__ void l_store(int* p, int i, int v) {
    __hip_atomic_store(&p[i], v, __ATOMIC_RELAXED, __HIP_MEMORY_SCOPE_WORKGROUP);
}
__device__ int l_find(int* lp, int x) {
    int p = l_load(lp, x);
    while (p != x) {
        int gp = l_load(lp, p);
        if (gp != p) l_store(lp, x, gp);
        x = p; p = gp;
    }
    return p;
}
__device__ void l_union(int* lp, int a, int b) {
    int ra = l_find(lp, a);
    int rb = l_find(lp, b);
    while (ra != rb) {
        if (ra > rb) { int t = ra; ra = rb; rb = t; }
        int old = atomicCAS(&lp[rb], rb, ra);
        if (old == rb) return;
        rb = l_find(lp, old);
        ra = l_find(lp, ra);
    }
}

// ---------------- stage kernels ----------------
// flags bit0 = active, bit1 = core
__global__ __launch_bounds__(THREADS) void k_init(const float* __restrict__ mask,
                                                  uint8_t* __restrict__ flags) {
    int i = blockIdx.x * THREADS + threadIdx.x;
    int r = i >> 11, c = i & (WW - 1);
    bool act = mask[i] > 0.1f;
    int cnt = 0;
    #pragma unroll
    for (int dr = -1; dr <= 1; ++dr) {
        int rr = r + dr;
        if (rr < 0 || rr >= HH) continue;
        #pragma unroll
        for (int dc = -1; dc <= 1; ++dc) {
            int cc = c + dc;
            if (cc < 0 || cc >= WW) continue;
            cnt += (mask[rr * WW + cc] > 0.1f) ? 1 : 0;
        }
    }
    bool core = act && (cnt >= 4);   // cnt includes self; MIN_SAMPLES = 4
    flags[i] = (uint8_t)((act ? 1 : 0) | (core ? 2 : 0));
}

// per-tile CC in LDS; writes parent[i] = global index of tile-local min-root.
// Local (row,col) order == global order within a tile, so local min-roots
// compose with the min-hook global merge to the exact global min label.
__global__ __launch_bounds__(THREADS) void k_local(const uint8_t* __restrict__ flags,
                                                   int* __restrict__ parent) {
    __shared__ uint8_t lc8[TILE];
    __shared__ int lp[TILE];
    int tile_x = blockIdx.x & 31, tile_y = blockIdx.x >> 5;
    int r0 = tile_y << 6, c0 = tile_x << 6;
    {   // stage 64 rows x 64B of flags into LDS (uint4 per thread)
        int row = threadIdx.x >> 2, chunk = threadIdx.x & 3;
        const uint4* src = (const uint4*)(flags + (size_t)(r0 + row) * WW + c0);
        ((uint4*)lc8)[row * 4 + chunk] = src[chunk];
    }
    for (int li = threadIdx.x; li < TILE; li += THREADS) lp[li] = li;
    __syncthreads();
    for (int li = threadIdx.x; li < TILE; li += THREADS) {
        if (!(lc8[li] & 2)) continue;
        int lr = li >> 6, lc = li & 63;
        if (lc > 0 && (lc8[li - 1] & 2)) l_union(lp, li, li - 1);
        if (lr > 0) {
            if (lc > 0  && (lc8[li - 65] & 2)) l_union(lp, li, li - 65);
            if (           (lc8[li - 64] & 2)) l_union(lp, li, li - 64);
            if (lc < 63 && (lc8[li - 63] & 2)) l_union(lp, li, li - 63);
        }
    }
    __syncthreads();
    for (int li = threadIdx.x; li < TILE; li += THREADS) {
        if (!(lc8[li] & 2)) continue;
        int root = li, p;
        while ((p = lp[root]) != root) root = p;   // lp stable after barrier
        int gi = (r0 + (li >> 6)) * WW + c0 + (li & 63);
        int gr = (r0 + (root >> 6)) * WW + c0 + (root & 63);
        parent[gi] = gr;
    }
}

// union only tile-crossing backward edges: 190 boundary pixels per tile
__global__ __launch_bounds__(THREADS) void k_merge(const uint8_t* __restrict__ flags,
                                                   int* __restrict__ parent) {
    int tile_x = blockIdx.x & 31, tile_y = blockIdx.x >> 5;
    int r0 = tile_y << 6, c0 = tile_x << 6;
    int t = threadIdx.x;
    int lr, lc;
    if (t < 64)       { lr = 0;       lc = t;  }
    else if (t < 127) { lr = t - 63;  lc = 0;  }
    else if (t < 190) { lr = t - 126; lc = 63; }
    else return;
    int r = r0 + lr, c = c0 + lc;
    int i = r * WW + c;
    if (!(flags[i] & 2)) return;
    if (lc == 0 && c > 0 && (flags[i - 1] & 2))                    // W crosses
        uf_union(parent, i, i - 1);
    if (r > 0) {
        if (lr == 0 && (flags[i - WW] & 2))                        // N crosses
            uf_union(parent, i, i - WW);
        if ((lr == 0 || lc == 0) && c > 0 && (flags[i - WW - 1] & 2))  // NW
            uf_union(parent, i, i - WW - 1);
        if ((lr == 0 || lc == 63) && c < WW - 1 && (flags[i - WW + 1] & 2)) // NE
            uf_union(parent, i, i - WW + 1);
    }
}

__global__ __launch_bounds__(THREADS) void k_flatten(const uint8_t* __restrict__ flags,
                                                     int* __restrict__ parent,
                                                     int* __restrict__ finalL) {
    int i = blockIdx.x * THREADS + threadIdx.x;
    finalL[i] = (flags[i] & 2) ? uf_find(parent, i) : BIGL;
}

// border assignment + per-label stats (wave-run agg -> LDS hash -> global)
__global__ __launch_bounds__(THREADS) void k_border_stats(
        const uint8_t* __restrict__ flags, const int* __restrict__ finalL,
        int* __restrict__ labfull, int* __restrict__ sizes,
        unsigned long long* __restrict__ colsum) {
    __shared__ int h_lab[HSZ];
    __shared__ int h_sz[HSZ];
    __shared__ unsigned long long h_cs[HSZ];
    for (int t = threadIdx.x; t < HSZ; t += THREADS) {
        h_lab[t] = -1; h_sz[t] = 0; h_cs[t] = 0;
    }
    __syncthreads();

    int i = blockIdx.x * THREADS + threadIdx.x;
    int f = flags[i];
    int lab = BIGL;
    if (f & 2) {
        lab = finalL[i];
    } else if (f & 1) {              // active non-core: min core label in 3x3
        int r = i >> 11, c = i & (WW - 1);
        int m = BIGL;
        #pragma unroll
        for (int dr = -1; dr <= 1; ++dr) {
            int rr = r + dr;
            if (rr < 0 || rr >= HH) continue;
            #pragma unroll
            for (int dc = -1; dc <= 1; ++dc) {
                int cc = c + dc;
                if (cc < 0 || cc >= WW) continue;
                int v = finalL[rr * WW + cc];
                if (v < m) m = v;
            }
        }
        lab = m;                     // BIGL if no core neighbor
    }
    labfull[i] = lab;

    // wave-level run aggregation (WW % 64 == 0: wave never crosses a row)
    int lane = threadIdx.x & 63;
    int labp = __shfl_up(lab, 1);
    bool head = (lane == 0) || (labp != lab);
    unsigned long long hm = __ballot(head);
    if (head && lab < BIGL) {
        unsigned long long rest = (hm >> lane) >> 1;
        int len = rest ? __ffsll((unsigned long long)rest) : (64 - lane);
        long long c0 = (long long)(i & (WW - 1));
        unsigned long long csum =
            (unsigned long long)(c0 * len + (long long)len * (len - 1) / 2);
        unsigned slot = (((unsigned)lab * 2654435761u) >> 20) & (HSZ - 1);
        for (;;) {
            int old = atomicCAS(&h_lab[slot], -1, lab);
            if (old == -1 || old == lab) {
                atomicAdd(&h_sz[slot], len);
                atomicAdd(&h_cs[slot], csum);
                break;
            }
            slot = (slot + 1) & (HSZ - 1);
        }
    }
    __syncthreads();
    for (int t = threadIdx.x; t < HSZ; t += THREADS) {
        int lb = h_lab[t];
        if (lb >= 0) {
            atomicAdd(&sizes[lb], h_sz[t]);
            atomicAdd(&colsum[lb], h_cs[t]);
        }
    }
}

__global__ __launch_bounds__(THREADS) void k_cands(const int* __restrict__ sizes,
                                                   const unsigned long long* __restrict__ colsum,
                                                   unsigned long long* __restrict__ cand,
                                                   int* __restrict__ counter) {
    int i = blockIdx.x * THREADS + threadIdx.x;
    int s = sizes[i];
    if (s >= MINCL) {
        float mean = (float)colsum[i] / (float)s;
        unsigned int mb = __float_as_uint(mean);      // mean >= 0: bit order = value order
        unsigned long long key = ((unsigned long long)mb << 32) | (unsigned int)i;
        int p = atomicAdd(counter, 1);
        cand[p] = key;
    }
}

// single block: 26 successive min-extractions; writes root -> channel map
__global__ __launch_bounds__(1024) void k_select(const unsigned long long* __restrict__ cand,
                                                 const int* __restrict__ counter,
                                                 signed char* __restrict__ chan) {
    __shared__ unsigned long long sm[1024];
    const int tid = threadIdx.x;
    const int n = *counter;
    unsigned long long prev = 0;
    for (int k = 0; k < NSLOTS; ++k) {
        unsigned long long local = ~0ull;
        for (int j = tid; j < n; j += 1024) {
            unsigned long long v = cand[j];
            if ((k == 0 || v > prev) && v < local) local = v;
        }
        sm[tid] = local;
        __syncthreads();
        for (int s = 512; s > 0; s >>= 1) {
            if (tid < s && sm[tid + s] < sm[tid]) sm[tid] = sm[tid + s];
            __syncthreads();
        }
        unsigned long long best = sm[0];
        __syncthreads();
        if (best == ~0ull) break;
        if (tid == 0) chan[(unsigned int)(best & 0xFFFFFFFFull)] = (signed char)k;
        prev = best;
    }
}

// one-hot 26xHxW int32 output, int4 stores
__global__ __launch_bounds__(THREADS) void k_output(const int* __restrict__ labfull,
                                                    const signed char* __restrict__ chan,
                                                    int* __restrict__ out) {
    int i4 = (blockIdx.x * THREADS + threadIdx.x) * 4;
    int chv[4];
    #pragma unroll
    for (int t = 0; t < 4; ++t) {
        int lab = labfull[i4 + t];
        chv[t] = (lab < BIGL) ? (int)chan[lab] : -1;
    }
    #pragma unroll
    for (int c = 0; c < NSLOTS; ++c) {
        int4 v;
        v.x = (chv[0] == c) ? 1 : 0;
        v.y = (chv[1] == c) ? 1 : 0;
        v.z = (chv[2] == c) ? 1 : 0;
        v.w = (chv[3] == c) ? 1 : 0;
        *(int4*)(out + (size_t)c * HWN + i4) = v;
    }
}

extern "C" void kernel_launch(void* const* d_in, const int* in_sizes, int n_in,
                              void* d_out, int out_size, void* d_ws, size_t ws_size,
                              hipStream_t stream) {
    const float* mask = (const float*)d_in[0];
    int* out = (int*)d_out;

    char* w = (char*)d_ws;
    int* parent                 = (int*)(w);                          //  8 MB (reused as labfull)
    int* finalL                 = (int*)(w + (size_t)HWN * 4);        //  8 MB
    int* sizes                  = (int*)(w + (size_t)HWN * 8);        //  8 MB
    unsigned long long* colsum  = (unsigned long long*)(w + (size_t)HWN * 12); // 16 MB
    uint8_t* flags              = (uint8_t*)(w + (size_t)HWN * 20);   //  2 MB
    signed char* chan           = (signed char*)(w + (size_t)HWN * 21); // 2 MB
    unsigned long long* cand    = (unsigned long long*)(w + (size_t)HWN * 22); // 560 KB
    int* counter                = (int*)(w + (size_t)HWN * 22 + MAXCAND * 8);

    // ws is re-poisoned 0xAA before every call — re-init what we accumulate into
    hipMemsetAsync(sizes, 0, (size_t)HWN * 4, stream);
    hipMemsetAsync(colsum, 0, (size_t)HWN * 8, stream);
    hipMemsetAsync(chan, 0xFF, (size_t)HWN, stream);    // -1 = no channel
    hipMemsetAsync(counter, 0, 4, stream);

    const int blocks = HWN / THREADS;   // 8192
    k_init        <<<blocks, THREADS, 0, stream>>>(mask, flags);
    k_local       <<<NTILES, THREADS, 0, stream>>>(flags, parent);
    k_merge       <<<NTILES, THREADS, 0, stream>>>(flags, parent);
    k_flatten     <<<blocks, THREADS, 0, stream>>>(flags, parent, finalL);
    k_border_stats<<<blocks, THREADS, 0, stream>>>(flags, finalL, parent, sizes, colsum);
    k_cands       <<<blocks, THREADS, 0, stream>>>(sizes, colsum, cand, counter);
    k_select      <<<1, 1024, 0, stream>>>(cand, counter, chan);
    k_output      <<<HWN / (4 * THREADS), THREADS, 0, stream>>>(parent, chan, out);
}

// Round 5
// 423.255 us; speedup vs baseline: 3.1820x; 1.0313x over previous
//
#include <hip/hip_runtime.h>
#include <stdint.h>

#define HH 1024
#define WW 2048
#define HWN (HH*WW)          // 2097152
#define BIGL HWN             // 'no cluster' sentinel
#define NSLOTS 26
#define MINCL 30
#define THREADS 256
#define MAXCAND 70000        // >= HWN/30 + 1
#define HSZ 512              // per-block LDS label-hash entries
#define TILE 4096            // 64x64 tile
#define NTILES 512           // (1024/64)*(2048/64)

// ---------------- global union-find (lock-free, min-root) ----------------
__device__ __forceinline__ int uf_load(int* p, int i) {
    return __hip_atomic_load(&p[i], __ATOMIC_RELAXED, __HIP_MEMORY_SCOPE_AGENT);
}
__device__ __forceinline__ void uf_store(int* p, int i, int v) {
    __hip_atomic_store(&p[i], v, __ATOMIC_RELAXED, __HIP_MEMORY_SCOPE_AGENT);
}
__device__ int uf_find(int* parent, int x) {
    int p = uf_load(parent, x);
    while (p != x) {
        int gp = uf_load(parent, p);
        if (gp != p) uf_store(parent, x, gp);   // path halving (benign race)
        x = p; p = gp;
    }
    return p;
}
__device__ void uf_union(int* parent, int a, int b) {
    int ra = uf_find(parent, a);
    int rb = uf_find(parent, b);
    while (ra != rb) {
        if (ra > rb) { int t = ra; ra = rb; rb = t; }   // hook larger under smaller
        int old = atomicCAS(&parent[rb], rb, ra);
        if (old == rb) return;
        rb = uf_find(parent, old);
        ra = uf_find(parent, ra);
    }
}

// ---------------- LDS union-find (block-local, min-root) ----------------
__device__ __forceinline__ int l_load(int* p, int i) {
    return __hip_atomic_load(&p[i], __ATOMIC_RELAXED, __HIP_MEMORY_SCOPE_WORKGROUP);
}
__device__ __forceinline__ void l_store(int* p, int i, int v) {
    __hip_atomic_store(&p[i], v, __ATOMIC_RELAXED, __HIP_MEMORY_SCOPE_WORKGROUP);
}
__device__ int l_find(int* lp, int x) {
    int p = l_load(lp, x);
    while (p != x) {
        int gp = l_load(lp, p);
        if (gp != p) l_store(lp, x, gp);
        x = p; p = gp;
    }
    return p;
}
__device__ void l_union(int* lp, int a, int b) {
    int ra = l_find(lp, a);
    int rb = l_find(lp, b);
    while (ra != rb) {
        if (ra > rb) { int t = ra; ra = rb; rb = t; }
        int old = atomicCAS(&lp[rb], rb, ra);
        if (old == rb) return;
        rb = l_find(lp, old);
        ra = l_find(lp, ra);
    }
}

// ---------------- fused init + per-tile CC ----------------
// Stage 66x66 active halo from mask, compute core flags in LDS, write flags,
// run tile-local min-root UF in LDS, write parent[i] = global(local root).
// Local (row,col) order == global order within a tile, so local min-roots
// compose with the min-hook global merge to the exact global min label.
__global__ __launch_bounds__(THREADS) void k_local(const float* __restrict__ mask,
                                                   uint8_t* __restrict__ flags,
                                                   int* __restrict__ parent) {
    __shared__ uint8_t lact[66 * 72];   // halo active map, row stride 72
    __shared__ uint8_t lc8[TILE];
    __shared__ int lp[TILE];
    int tile_x = blockIdx.x & 31, tile_y = blockIdx.x >> 5;
    int r0 = tile_y << 6, c0 = tile_x << 6;
    int tx = threadIdx.x & 15, ty = threadIdx.x >> 4;
    for (int yy = ty; yy < 66; yy += 16) {
        int gr = r0 - 1 + yy;
        for (int xx = tx; xx < 66; xx += 16) {
            int gc = c0 - 1 + xx;
            bool a = false;
            if ((unsigned)gr < HH && (unsigned)gc < WW)
                a = mask[gr * WW + gc] > 0.1f;
            lact[yy * 72 + xx] = a ? 1 : 0;
        }
    }
    __syncthreads();
    for (int li = threadIdx.x; li < TILE; li += THREADS) {
        int lr = li >> 6, lc = li & 63;
        int b = (lr + 1) * 72 + (lc + 1);
        int a = lact[b];
        int cnt = lact[b - 73] + lact[b - 72] + lact[b - 71]
                + lact[b - 1]  + a           + lact[b + 1]
                + lact[b + 71] + lact[b + 72] + lact[b + 73];
        lc8[li] = (uint8_t)(a | ((a && cnt >= 4) ? 2 : 0));  // MIN_SAMPLES=4 incl self
        lp[li] = li;
    }
    __syncthreads();
    {   // flags -> global, 16B per thread
        int row = threadIdx.x >> 2, chunk = threadIdx.x & 3;
        ((uint4*)(flags + (size_t)(r0 + row) * WW + c0))[chunk] =
            ((const uint4*)lc8)[row * 4 + chunk];
    }
    for (int li = threadIdx.x; li < TILE; li += THREADS) {
        if (!(lc8[li] & 2)) continue;
        int lr = li >> 6, lc = li & 63;
        if (lc > 0 && (lc8[li - 1] & 2)) l_union(lp, li, li - 1);
        if (lr > 0) {
            if (lc > 0  && (lc8[li - 65] & 2)) l_union(lp, li, li - 65);
            if (           (lc8[li - 64] & 2)) l_union(lp, li, li - 64);
            if (lc < 63 && (lc8[li - 63] & 2)) l_union(lp, li, li - 63);
        }
    }
    __syncthreads();
    for (int li = threadIdx.x; li < TILE; li += THREADS) {
        if (!(lc8[li] & 2)) continue;
        int root = li, p;
        while ((p = lp[root]) != root) root = p;   // lp stable after barrier
        int gi = (r0 + (li >> 6)) * WW + c0 + (li & 63);
        int gr = (r0 + (root >> 6)) * WW + c0 + (root & 63);
        parent[gi] = gr;
    }
}

// union only tile-crossing edges, with adjacency collapse + wave run-dedupe.
// Collapse: if N core, NW/NE are locally unioned with N in the above tile;
// if W core, NW is locally unioned with W in the left tile; if E core, NE is
// reached via right tile's (W-edge + local N-edge). Corners handled explicitly.
__global__ __launch_bounds__(THREADS) void k_merge(const uint8_t* __restrict__ flags,
                                                   int* __restrict__ parent) {
    int tile_x = blockIdx.x & 31, tile_y = blockIdx.x >> 5;
    int r0 = tile_y << 6, c0 = tile_x << 6;
    int t = threadIdx.x;
    int lane = t & 63;

    if (t < 64) {                                    // top row, lr=0, lc=t
        int r = r0, c = c0 + t, i = r * WW + c;
        bool selfC = (flags[i] & 2) != 0;
        bool nC = false, nwC = false, neC = false;
        if (selfC && r > 0) {
            nC  = (flags[i - WW] & 2) != 0;
            nwC = (c > 0)      && (flags[i - WW - 1] & 2);
            neC = (c < WW - 1) && (flags[i - WW + 1] & 2);
        }
        int did = 0, ra = -1, rb = -1;
        if (selfC && r > 0 && nC) { ra = uf_find(parent, i); rb = uf_find(parent, i - WW); did = 1; }
        int pra = __shfl_up(ra, 1), prb = __shfl_up(rb, 1), pdid = __shfl_up(did, 1);
        bool head = (lane == 0) || !pdid || pra != ra || prb != rb;
        if (did && head) uf_union(parent, ra, rb);
        if (selfC && r > 0) {
            if (t == 0) {
                if (nwC) uf_union(parent, i, i - WW - 1);          // diag tile
                if (!nC && neC) uf_union(parent, i, i - WW + 1);
            } else if (t == 63) {
                if (!nC && nwC) uf_union(parent, i, i - WW - 1);
                if (neC) {                                          // NE in diag tile
                    bool eC = (c < WW - 1) && (flags[i + 1] & 2);
                    if (!eC) uf_union(parent, i, i - WW + 1);
                    // else: us~E (right tile corner W-edge) and E~NE (its N-edge)
                }
            } else if (!nC) {
                if (nwC) uf_union(parent, i, i - WW - 1);
                if (neC) uf_union(parent, i, i - WW + 1);
            }
        }
        if (t == 0 && selfC && c > 0 && (flags[i - 1] & 2))        // corner W edge
            uf_union(parent, i, i - 1);
    } else if (t < 127) {                            // left col, lr=1..63, lc=0
        int lr = t - 63;
        int r = r0 + lr, c = c0, i = r * WW + c;
        bool selfC = (flags[i] & 2) != 0;
        bool wC = false, nwC = false;
        if (selfC && c > 0) {
            wC  = (flags[i - 1] & 2) != 0;
            nwC = (flags[i - WW - 1] & 2) != 0;      // r >= 1 guaranteed (lr>=1)
        }
        int did = 0, ra = -1, rb = -1;
        if (selfC && wC) { ra = uf_find(parent, i); rb = uf_find(parent, i - 1); did = 1; }
        int pra = __shfl_up(ra, 1), prb = __shfl_up(rb, 1), pdid = __shfl_up(did, 1);
        bool head = (lane == 0) || !pdid || pra != ra || prb != rb;
        if (did && head) uf_union(parent, ra, rb);
        if (selfC && !wC && nwC) uf_union(parent, i, i - WW - 1);  // if wC: NW~W local in left tile
    } else if (t < 190) {                            // right col, lr=1..63, lc=63
        int lr = t - 126;
        int r = r0 + lr, c = c0 + 63, i = r * WW + c;
        bool selfC = (flags[i] & 2) != 0;
        if (selfC && c < WW - 1) {
            bool neC = (flags[i - WW + 1] & 2) != 0;
            bool eC  = (flags[i + 1] & 2) != 0;
            if (neC && !eC) uf_union(parent, i, i - WW + 1);
            // if eC: us~E (right tile W-edge) and E~NE (right tile local N-edge)
        }
    }
}

// border assignment + per-label stats; labels via on-the-fly uf_find
// (k_flatten pass eliminated). Wave-run agg -> LDS hash -> global atomics.
__global__ __launch_bounds__(THREADS) void k_border_stats(
        const uint8_t* __restrict__ flags, int* __restrict__ parent,
        int* __restrict__ labfull, int* __restrict__ sizes,
        unsigned long long* __restrict__ colsum) {
    __shared__ int h_lab[HSZ];
    __shared__ int h_sz[HSZ];
    __shared__ unsigned long long h_cs[HSZ];
    for (int t = threadIdx.x; t < HSZ; t += THREADS) {
        h_lab[t] = -1; h_sz[t] = 0; h_cs[t] = 0;
    }
    __syncthreads();

    int i = blockIdx.x * THREADS + threadIdx.x;
    int f = flags[i];
    int lab = BIGL;
    if (f & 2) {
        lab = uf_find(parent, i);
    } else if (f & 1) {              // active non-core: min core-neighbor root in 3x3
        int r = i >> 11, c = i & (WW - 1);
        int m = BIGL;
        #pragma unroll
        for (int dr = -1; dr <= 1; ++dr) {
            int rr = r + dr;
            if (rr < 0 || rr >= HH) continue;
            #pragma unroll
            for (int dc = -1; dc <= 1; ++dc) {
                int cc = c + dc;
                if (cc < 0 || cc >= WW) continue;
                int n = rr * WW + cc;
                if (flags[n] & 2) {
                    int v = uf_find(parent, n);
                    if (v < m) m = v;
                }
            }
        }
        lab = m;                     // BIGL if no core neighbor
    }
    labfull[i] = lab;

    // wave-level run aggregation (WW % 64 == 0: wave never crosses a row)
    int lane = threadIdx.x & 63;
    int labp = __shfl_up(lab, 1);
    bool head = (lane == 0) || (labp != lab);
    unsigned long long hm = __ballot(head);
    if (head && lab < BIGL) {
        unsigned long long rest = (hm >> lane) >> 1;
        int len = rest ? __ffsll((unsigned long long)rest) : (64 - lane);
        long long c0 = (long long)(i & (WW - 1));
        unsigned long long csum =
            (unsigned long long)(c0 * len + (long long)len * (len - 1) / 2);
        unsigned slot = (((unsigned)lab * 2654435761u) >> 20) & (HSZ - 1);
        for (;;) {
            int old = atomicCAS(&h_lab[slot], -1, lab);
            if (old == -1 || old == lab) {
                atomicAdd(&h_sz[slot], len);
                atomicAdd(&h_cs[slot], csum);
                break;
            }
            slot = (slot + 1) & (HSZ - 1);
        }
    }
    __syncthreads();
    for (int t = threadIdx.x; t < HSZ; t += THREADS) {
        int lb = h_lab[t];
        if (lb >= 0) {
            atomicAdd(&sizes[lb], h_sz[t]);
            atomicAdd(&colsum[lb], h_cs[t]);
        }
    }
}

__global__ __launch_bounds__(THREADS) void k_cands(const int* __restrict__ sizes,
                                                   const unsigned long long* __restrict__ colsum,
                                                   unsigned long long* __restrict__ cand,
                                                   int* __restrict__ counter) {
    int i = blockIdx.x * THREADS + threadIdx.x;
    int s = sizes[i];
    if (s >= MINCL) {
        float mean = (float)colsum[i] / (float)s;
        unsigned int mb = __float_as_uint(mean);      // mean >= 0: bit order = value order
        unsigned long long key = ((unsigned long long)mb << 32) | (unsigned int)i;
        int p = atomicAdd(counter, 1);
        cand[p] = key;
    }
}

// single block: 26 successive min-extractions; writes root -> channel map
__global__ __launch_bounds__(1024) void k_select(const unsigned long long* __restrict__ cand,
                                                 const int* __restrict__ counter,
                                                 signed char* __restrict__ chan) {
    __shared__ unsigned long long sm[1024];
    const int tid = threadIdx.x;
    const int n = *counter;
    unsigned long long prev = 0;
    for (int k = 0; k < NSLOTS; ++k) {
        unsigned long long local = ~0ull;
        for (int j = tid; j < n; j += 1024) {
            unsigned long long v = cand[j];
            if ((k == 0 || v > prev) && v < local) local = v;
        }
        sm[tid] = local;
        __syncthreads();
        for (int s = 512; s > 0; s >>= 1) {
            if (tid < s && sm[tid + s] < sm[tid]) sm[tid] = sm[tid + s];
            __syncthreads();
        }
        unsigned long long best = sm[0];
        __syncthreads();
        if (best == ~0ull) break;
        if (tid == 0) chan[(unsigned int)(best & 0xFFFFFFFFull)] = (signed char)k;
        prev = best;
    }
}

// one-hot 26xHxW int32 output, int4 stores
__global__ __launch_bounds__(THREADS) void k_output(const int* __restrict__ labfull,
                                                    const signed char* __restrict__ chan,
                                                    int* __restrict__ out) {
    int i4 = (blockIdx.x * THREADS + threadIdx.x) * 4;
    int chv[4];
    #pragma unroll
    for (int t = 0; t < 4; ++t) {
        int lab = labfull[i4 + t];
        chv[t] = (lab < BIGL) ? (int)chan[lab] : -1;
    }
    #pragma unroll
    for (int c = 0; c < NSLOTS; ++c) {
        int4 v;
        v.x = (chv[0] == c) ? 1 : 0;
        v.y = (chv[1] == c) ? 1 : 0;
        v.z = (chv[2] == c) ? 1 : 0;
        v.w = (chv[3] == c) ? 1 : 0;
        *(int4*)(out + (size_t)c * HWN + i4) = v;
    }
}

extern "C" void kernel_launch(void* const* d_in, const int* in_sizes, int n_in,
                              void* d_out, int out_size, void* d_ws, size_t ws_size,
                              hipStream_t stream) {
    const float* mask = (const float*)d_in[0];
    int* out = (int*)d_out;

    char* w = (char*)d_ws;
    int* parent                 = (int*)(w);                          //  8 MB
    int* labfull                = (int*)(w + (size_t)HWN * 4);        //  8 MB
    int* sizes                  = (int*)(w + (size_t)HWN * 8);        //  8 MB
    unsigned long long* colsum  = (unsigned long long*)(w + (size_t)HWN * 12); // 16 MB
    uint8_t* flags              = (uint8_t*)(w + (size_t)HWN * 20);   //  2 MB
    signed char* chan           = (signed char*)(w + (size_t)HWN * 21); // 2 MB
    unsigned long long* cand    = (unsigned long long*)(w + (size_t)HWN * 22); // 560 KB
    int* counter                = (int*)(w + (size_t)HWN * 22 + MAXCAND * 8);

    // ws is re-poisoned 0xAA before every call — re-init what we accumulate into
    hipMemsetAsync(sizes, 0, (size_t)HWN * 4, stream);
    hipMemsetAsync(colsum, 0, (size_t)HWN * 8, stream);
    hipMemsetAsync(chan, 0xFF, (size_t)HWN, stream);    // -1 = no channel
    hipMemsetAsync(counter, 0, 4, stream);

    const int blocks = HWN / THREADS;   // 8192
    k_local       <<<NTILES, THREADS, 0, stream>>>(mask, flags, parent);
    k_merge       <<<NTILES, THREADS, 0, stream>>>(flags, parent);
    k_border_stats<<<blocks, THREADS, 0, stream>>>(flags, parent, labfull, sizes, colsum);
    k_cands       <<<blocks, THREADS, 0, stream>>>(sizes, colsum, cand, counter);
    k_select      <<<1, 1024, 0, stream>>>(cand, counter, chan);
    k_output      <<<HWN / (4 * THREADS), THREADS, 0, stream>>>(labfull, chan, out);
}